// Round 11
// baseline (577.144 us; speedup 1.0000x reference)
//
#include <hip/hip_runtime.h>

#define B_ 2
#define N_ 1024
#define C_ 1024
#define H_ 16
#define HD_ 64
#define PK 40  // ushort stride per LDS row (80B): 16B-aligned b128, 2-way banks

typedef short short8 __attribute__((ext_vector_type(8)));
typedef float f32x4 __attribute__((ext_vector_type(4)));
typedef unsigned short ushort_t;

// ---------- wave-wide (64-lane) helpers ----------
__device__ __forceinline__ float wsumf(float x) {
#pragma unroll
  for (int off = 32; off; off >>= 1) x += __shfl_xor(x, off, 64);
  return x;
}
__device__ __forceinline__ unsigned orderu(float f) {
  unsigned b = __float_as_uint(f);
  return (b & 0x80000000u) ? ~b : (b | 0x80000000u);
}
__device__ __forceinline__ float iorderu(unsigned x) {
  unsigned b = (x & 0x80000000u) ? (x & 0x7FFFFFFFu) : ~x;
  return __uint_as_float(b);
}

// 2-term split f32 -> packed u32: hi bf16 low16, lo bf16 high16 (RTNE)
__device__ __forceinline__ unsigned splitf2(float f) {
  unsigned u = __float_as_uint(f);
  unsigned t = (u + 0x7fffu + ((u >> 16) & 1u)) & 0xffff0000u;
  float r = f - __uint_as_float(t);  // exact
  unsigned v = __float_as_uint(r);
  unsigned tv = v + 0x7fffu + ((v >> 16) & 1u);
  return (t >> 16) | (tv & 0xffff0000u);
}
// 3-term split: hm = hi|mid packed u32, lo = third bf16 term
__device__ __forceinline__ void splitf3(float f, unsigned& hm, ushort_t& lo) {
  unsigned u = __float_as_uint(f);
  unsigned t = (u + 0x7fffu + ((u >> 16) & 1u)) & 0xffff0000u;
  float r1 = f - __uint_as_float(t);  // exact
  unsigned v = __float_as_uint(r1);
  unsigned tv = (v + 0x7fffu + ((v >> 16) & 1u)) & 0xffff0000u;
  float r2 = r1 - __uint_as_float(tv);  // exact
  unsigned w = __float_as_uint(r2);
  unsigned tw = w + 0x7fffu + ((w >> 16) & 1u);
  hm = (t >> 16) | tv;
  lo = (ushort_t)(tw >> 16);
}

// ---------- NKAT per-token factor ----------
__global__ __launch_bounds__(64) void factor_kernel(
    const float* __restrict__ x, const float* __restrict__ alpha_p,
    const float* __restrict__ beta_p, float* __restrict__ fac) {
  const int row = blockIdx.x;
  const int lane = threadIdx.x;
  const float4* xr = (const float4*)(x + (size_t)row * C_);
  float s = 0.f, ss = 0.f;
#pragma unroll
  for (int j = 0; j < 4; ++j) {
    float4 v = xr[lane + 64 * j];
    s += v.x + v.y + v.z + v.w;
    ss += v.x * v.x + v.y * v.y + v.z * v.z + v.w * v.w;
  }
  s = wsumf(s);
  ss = wsumf(ss);
  const float mean = s * (1.f / 1024.f);
  const float var = ss * (1.f / 1024.f) - mean * mean;
  const float theta =
      alpha_p[0] * tanhf(mean) + beta_p[0] * (1.f / (1.f + __expf(-var)));
  if (lane == 0) fac[row] = 1.f + 0.45125f * theta;  // lc = 0.5*0.95^2
}

// ---------- split x (row-major) into 3 bf16 planes ----------
__global__ __launch_bounds__(256) void split_x_kernel(
    const float* __restrict__ x, ushort_t* __restrict__ xh,
    ushort_t* __restrict__ xm, ushort_t* __restrict__ xl) {
  const int i = (blockIdx.x * 256 + threadIdx.x) * 4;
  const float4 v = *(const float4*)(x + i);
  unsigned hm0, hm1, hm2, hm3;
  ushort_t l0, l1, l2, l3;
  splitf3(v.x, hm0, l0);
  splitf3(v.y, hm1, l1);
  splitf3(v.z, hm2, l2);
  splitf3(v.w, hm3, l3);
  *(ushort4*)(xh + i) =
      make_ushort4(hm0 & 0xffffu, hm1 & 0xffffu, hm2 & 0xffffu, hm3 & 0xffffu);
  *(ushort4*)(xm + i) =
      make_ushort4(hm0 >> 16, hm1 >> 16, hm2 >> 16, hm3 >> 16);
  *(ushort4*)(xl + i) = make_ushort4(l0, l1, l2, l3);
}

// ---------- transpose + split weight [K][J] -> planes [J][K] ----------
__global__ __launch_bounds__(256) void split_wT_kernel(
    const float* __restrict__ src, int ldsrc, ushort_t* __restrict__ th,
    ushort_t* __restrict__ tm, ushort_t* __restrict__ tl) {
  __shared__ float tile[64][65];
  const int t = threadIdx.x;
  const int k0 = blockIdx.y * 64, j0 = blockIdx.x * 64;
  const int rr = t >> 4, cc4 = (t & 15) * 4;
#pragma unroll
  for (int p = 0; p < 4; ++p) {
    const float4 v =
        *(const float4*)(src + (size_t)(k0 + rr + 16 * p) * ldsrc + j0 + cc4);
    tile[rr + 16 * p][cc4 + 0] = v.x;
    tile[rr + 16 * p][cc4 + 1] = v.y;
    tile[rr + 16 * p][cc4 + 2] = v.z;
    tile[rr + 16 * p][cc4 + 3] = v.w;
  }
  __syncthreads();
  const int j = t >> 2, kc = (t & 3) * 16;
#pragma unroll
  for (int half = 0; half < 2; ++half) {
    unsigned hw[4], mw[4], lw[4];
#pragma unroll
    for (int e = 0; e < 4; ++e) {
      unsigned hmA, hmB;
      ushort_t loA, loB;
      splitf3(tile[kc + half * 8 + 2 * e][j], hmA, loA);
      splitf3(tile[kc + half * 8 + 2 * e + 1][j], hmB, loB);
      hw[e] = (hmA & 0xffffu) | ((hmB & 0xffffu) << 16);
      mw[e] = (hmA >> 16) | (hmB & 0xffff0000u);
      lw[e] = (unsigned)loA | ((unsigned)loB << 16);
    }
    const size_t o = (size_t)(j0 + j) * 1024 + k0 + kc + half * 8;
    *(uint4*)(th + o) = make_uint4(hw[0], hw[1], hw[2], hw[3]);
    *(uint4*)(tm + o) = make_uint4(mw[0], mw[1], mw[2], mw[3]);
    *(uint4*)(tl + o) = make_uint4(lw[0], lw[1], lw[2], lw[3]);
  }
}

// ---------- qk GEMM: 3-plane (6-product) MFMA, plane-staged ----------
__global__ __launch_bounds__(256) void gemm_qk_kernel(
    const ushort_t* __restrict__ xh, const ushort_t* __restrict__ xm,
    const ushort_t* __restrict__ xl, const ushort_t* __restrict__ wh,
    const ushort_t* __restrict__ wm, const ushort_t* __restrict__ wl,
    float* __restrict__ q, float* __restrict__ ktb) {
  __shared__ ushort_t Ah[128 * PK], Am[128 * PK], Al[128 * PK];
  __shared__ ushort_t Bh[128 * PK], Bm2[128 * PK], Bl[128 * PK];
  f32x4 acc[4][4];
#pragma unroll
  for (int i = 0; i < 4; ++i)
#pragma unroll
    for (int j = 0; j < 4; ++j) acc[i][j] = (f32x4){0.f, 0.f, 0.f, 0.f};
  const int tid = threadIdx.x;
  const int lane = tid & 63;
  const int m0 = blockIdx.y * 128, n0 = blockIdx.x * 128;
  const int wro = ((tid >> 7) & 1) * 64;
  const int wco = ((tid >> 6) & 1) * 64;
  const int srow = tid >> 1, soff = (tid & 1) * 16;
  const int fr = lane & 15, fk = (lane >> 4) * 8;
  const size_t ga = (size_t)(m0 + srow) * 1024 + soff;
  const size_t gb = (size_t)(n0 + srow) * 1024 + soff;

  uint4 aR[3][2], bR[3][2];
  aR[0][0] = *(const uint4*)(xh + ga);
  aR[0][1] = *(const uint4*)(xh + ga + 8);
  aR[1][0] = *(const uint4*)(xm + ga);
  aR[1][1] = *(const uint4*)(xm + ga + 8);
  aR[2][0] = *(const uint4*)(xl + ga);
  aR[2][1] = *(const uint4*)(xl + ga + 8);
  bR[0][0] = *(const uint4*)(wh + gb);
  bR[0][1] = *(const uint4*)(wh + gb + 8);
  bR[1][0] = *(const uint4*)(wm + gb);
  bR[1][1] = *(const uint4*)(wm + gb + 8);
  bR[2][0] = *(const uint4*)(wl + gb);
  bR[2][1] = *(const uint4*)(wl + gb + 8);

  const int lbase = srow * PK + soff;
  for (int kt = 0; kt < 32; ++kt) {
    __syncthreads();  // prior frag reads done
    *(uint4*)&Ah[lbase] = aR[0][0];
    *(uint4*)&Ah[lbase + 8] = aR[0][1];
    *(uint4*)&Am[lbase] = aR[1][0];
    *(uint4*)&Am[lbase + 8] = aR[1][1];
    *(uint4*)&Al[lbase] = aR[2][0];
    *(uint4*)&Al[lbase + 8] = aR[2][1];
    *(uint4*)&Bh[lbase] = bR[0][0];
    *(uint4*)&Bh[lbase + 8] = bR[0][1];
    *(uint4*)&Bm2[lbase] = bR[1][0];
    *(uint4*)&Bm2[lbase + 8] = bR[1][1];
    *(uint4*)&Bl[lbase] = bR[2][0];
    *(uint4*)&Bl[lbase + 8] = bR[2][1];
    __syncthreads();
    if (kt + 1 < 32) {  // prefetch next k-tile; hides under MFMA
      const size_t oa = ga + (size_t)(kt + 1) * 32;
      const size_t ob = gb + (size_t)(kt + 1) * 32;
      aR[0][0] = *(const uint4*)(xh + oa);
      aR[0][1] = *(const uint4*)(xh + oa + 8);
      aR[1][0] = *(const uint4*)(xm + oa);
      aR[1][1] = *(const uint4*)(xm + oa + 8);
      aR[2][0] = *(const uint4*)(xl + oa);
      aR[2][1] = *(const uint4*)(xl + oa + 8);
      bR[0][0] = *(const uint4*)(wh + ob);
      bR[0][1] = *(const uint4*)(wh + ob + 8);
      bR[1][0] = *(const uint4*)(wm + ob);
      bR[1][1] = *(const uint4*)(wm + ob + 8);
      bR[2][0] = *(const uint4*)(wl + ob);
      bR[2][1] = *(const uint4*)(wl + ob + 8);
    }
    short8 fah[4], fam[4], fal[4];
#pragma unroll
    for (int rt = 0; rt < 4; ++rt) {
      const int ba = (wro + rt * 16 + fr) * PK + fk;
      fah[rt] = *(const short8*)&Ah[ba];
      fam[rt] = *(const short8*)&Am[ba];
      fal[rt] = *(const short8*)&Al[ba];
    }
#pragma unroll
    for (int ct = 0; ct < 4; ++ct) {
      const int bb = (wco + ct * 16 + fr) * PK + fk;
      const short8 fbh = *(const short8*)&Bh[bb];
      const short8 fbm = *(const short8*)&Bm2[bb];
      const short8 fbl = *(const short8*)&Bl[bb];
#pragma unroll
      for (int rt = 0; rt < 4; ++rt) {
        f32x4 c = acc[rt][ct];
        c = __builtin_amdgcn_mfma_f32_16x16x32_bf16(fah[rt], fbl, c, 0, 0, 0);
        c = __builtin_amdgcn_mfma_f32_16x16x32_bf16(fal[rt], fbh, c, 0, 0, 0);
        c = __builtin_amdgcn_mfma_f32_16x16x32_bf16(fam[rt], fbm, c, 0, 0, 0);
        c = __builtin_amdgcn_mfma_f32_16x16x32_bf16(fah[rt], fbm, c, 0, 0, 0);
        c = __builtin_amdgcn_mfma_f32_16x16x32_bf16(fam[rt], fbh, c, 0, 0, 0);
        c = __builtin_amdgcn_mfma_f32_16x16x32_bf16(fah[rt], fbh, c, 0, 0, 0);
        acc[rt][ct] = c;
      }
    }
  }

  const int rbase = (lane >> 4) * 4, cc = lane & 15;
#pragma unroll
  for (int rt = 0; rt < 4; ++rt) {
    const int m = m0 + wro + rt * 16 + rbase;
    const int bb2 = m >> 10, nn = m & 1023;
#pragma unroll
    for (int ct = 0; ct < 4; ++ct) {
      const int j = n0 + wco + ct * 16 + cc;
      const int sel = j >> 10, hh = (j >> 6) & 15, d0 = j & 63;
      const f32x4 c = acc[rt][ct];
      if (sel == 1) {  // K transposed: contiguous along token index nn
        *(float4*)(ktb + (((size_t)(bb2 * 16 + hh) * HD_ + d0) << 10) + nn) =
            make_float4(c[0], c[1], c[2], c[3]);
      } else {
        float* dst = q + (((size_t)(bb2 * 16 + hh) << 10) + nn) * HD_ + d0;
        dst[0] = c[0];
        dst[HD_] = c[1];
        dst[2 * HD_] = c[2];
        dst[3 * HD_] = c[3];
      }
    }
  }
}

// ---------- 2-plane (3-product) MFMA core: plane-staged ----------
__device__ __forceinline__ void mfma_core3p(
    const ushort_t* __restrict__ Ahp, const ushort_t* __restrict__ Amp,
    const ushort_t* __restrict__ Bhp, const ushort_t* __restrict__ Bmp,
    int m0, int n0, ushort_t* Ah, ushort_t* Am, ushort_t* Bh, ushort_t* Bm2,
    f32x4 acc[4][4]) {
  const int tid = threadIdx.x;
  const int lane = tid & 63;
  const int wro = ((tid >> 7) & 1) * 64;
  const int wco = ((tid >> 6) & 1) * 64;
  const int srow = tid >> 1, soff = (tid & 1) * 16;
  const int fr = lane & 15, fk = (lane >> 4) * 8;
  const size_t ga = (size_t)(m0 + srow) * 1024 + soff;
  const size_t gb = (size_t)(n0 + srow) * 1024 + soff;

  uint4 aR[2][2], bR[2][2];
  aR[0][0] = *(const uint4*)(Ahp + ga);
  aR[0][1] = *(const uint4*)(Ahp + ga + 8);
  aR[1][0] = *(const uint4*)(Amp + ga);
  aR[1][1] = *(const uint4*)(Amp + ga + 8);
  bR[0][0] = *(const uint4*)(Bhp + gb);
  bR[0][1] = *(const uint4*)(Bhp + gb + 8);
  bR[1][0] = *(const uint4*)(Bmp + gb);
  bR[1][1] = *(const uint4*)(Bmp + gb + 8);

  const int lbase = srow * PK + soff;
  for (int kt = 0; kt < 32; ++kt) {
    __syncthreads();
    *(uint4*)&Ah[lbase] = aR[0][0];
    *(uint4*)&Ah[lbase + 8] = aR[0][1];
    *(uint4*)&Am[lbase] = aR[1][0];
    *(uint4*)&Am[lbase + 8] = aR[1][1];
    *(uint4*)&Bh[lbase] = bR[0][0];
    *(uint4*)&Bh[lbase + 8] = bR[0][1];
    *(uint4*)&Bm2[lbase] = bR[1][0];
    *(uint4*)&Bm2[lbase + 8] = bR[1][1];
    __syncthreads();
    if (kt + 1 < 32) {
      const size_t oa = ga + (size_t)(kt + 1) * 32;
      const size_t ob = gb + (size_t)(kt + 1) * 32;
      aR[0][0] = *(const uint4*)(Ahp + oa);
      aR[0][1] = *(const uint4*)(Ahp + oa + 8);
      aR[1][0] = *(const uint4*)(Amp + oa);
      aR[1][1] = *(const uint4*)(Amp + oa + 8);
      bR[0][0] = *(const uint4*)(Bhp + ob);
      bR[0][1] = *(const uint4*)(Bhp + ob + 8);
      bR[1][0] = *(const uint4*)(Bmp + ob);
      bR[1][1] = *(const uint4*)(Bmp + ob + 8);
    }
    short8 fah[4], fam[4];
#pragma unroll
    for (int rt = 0; rt < 4; ++rt) {
      const int ba = (wro + rt * 16 + fr) * PK + fk;
      fah[rt] = *(const short8*)&Ah[ba];
      fam[rt] = *(const short8*)&Am[ba];
    }
#pragma unroll
    for (int ct = 0; ct < 4; ++ct) {
      const int bb = (wco + ct * 16 + fr) * PK + fk;
      const short8 fbh = *(const short8*)&Bh[bb];
      const short8 fbm = *(const short8*)&Bm2[bb];
#pragma unroll
      for (int rt = 0; rt < 4; ++rt) {
        f32x4 c = acc[rt][ct];
        c = __builtin_amdgcn_mfma_f32_16x16x32_bf16(fah[rt], fbm, c, 0, 0, 0);
        c = __builtin_amdgcn_mfma_f32_16x16x32_bf16(fam[rt], fbh, c, 0, 0, 0);
        c = __builtin_amdgcn_mfma_f32_16x16x32_bf16(fah[rt], fbh, c, 0, 0, 0);
        acc[rt][ct] = c;
      }
    }
  }
}

// ---------- v: w_qkv cols 2048..3071 -> v (B,H,N,HD) ----------
__global__ __launch_bounds__(256) void gemm_v_kernel(
    const ushort_t* __restrict__ xh, const ushort_t* __restrict__ xm,
    const ushort_t* __restrict__ wh, const ushort_t* __restrict__ wm,
    float* __restrict__ v) {
  __shared__ ushort_t Ah[128 * PK], Am[128 * PK];
  __shared__ ushort_t Bh[128 * PK], Bm2[128 * PK];
  f32x4 acc[4][4];
#pragma unroll
  for (int i = 0; i < 4; ++i)
#pragma unroll
    for (int j = 0; j < 4; ++j) acc[i][j] = (f32x4){0.f, 0.f, 0.f, 0.f};
  const int m0 = blockIdx.y * 128, n0 = 2048 + blockIdx.x * 128;
  mfma_core3p(xh, xm, wh, wm, m0, n0, Ah, Am, Bh, Bm2, acc);

  const int lane = threadIdx.x & 63;
  const int wro = ((threadIdx.x >> 7) & 1) * 64;
  const int wco = ((threadIdx.x >> 6) & 1) * 64;
  const int rbase = (lane >> 4) * 4, cc = lane & 15;
#pragma unroll
  for (int rt = 0; rt < 4; ++rt) {
    const int m = m0 + wro + rt * 16 + rbase;
    const int bb = m >> 10, nn = m & 1023;
#pragma unroll
    for (int ct = 0; ct < 4; ++ct) {
      const int jv = (n0 - 2048) + wco + ct * 16 + cc;
      const int hh = (jv >> 6) & 15, d0 = jv & 63;
      const f32x4 c = acc[rt][ct];
      float* dst = v + (((size_t)(bb * 16 + hh) << 10) + nn) * HD_ + d0;
      dst[0] = c[0];
      dst[HD_] = c[1];
      dst[2 * HD_] = c[2];
      dst[3 * HD_] = c[3];
    }
  }
}

// ---------- out = attn_out @ w_out + b_out (plane inputs) ----------
__global__ __launch_bounds__(256) void gemm_out_kernel(
    const ushort_t* __restrict__ aoh, const ushort_t* __restrict__ aom,
    const ushort_t* __restrict__ wh, const ushort_t* __restrict__ wm,
    const float* __restrict__ bias, float* __restrict__ out) {
  __shared__ ushort_t Ah[128 * PK], Am[128 * PK];
  __shared__ ushort_t Bh[128 * PK], Bm2[128 * PK];
  f32x4 acc[4][4];
#pragma unroll
  for (int i = 0; i < 4; ++i)
#pragma unroll
    for (int j = 0; j < 4; ++j) acc[i][j] = (f32x4){0.f, 0.f, 0.f, 0.f};
  const int m0 = blockIdx.y * 128, n0 = blockIdx.x * 128;
  mfma_core3p(aoh, aom, wh, wm, m0, n0, Ah, Am, Bh, Bm2, acc);

  const int lane = threadIdx.x & 63;
  const int wro = ((threadIdx.x >> 7) & 1) * 64;
  const int wco = ((threadIdx.x >> 6) & 1) * 64;
  const int rbase = (lane >> 4) * 4, cc = lane & 15;
#pragma unroll
  for (int rt = 0; rt < 4; ++rt) {
    const int m = m0 + wro + rt * 16 + rbase;
#pragma unroll
    for (int ct = 0; ct < 4; ++ct) {
      const int j = n0 + wco + ct * 16 + cc;
      const float bj = bias[j];
      const f32x4 c = acc[rt][ct];
      float* dst = out + (size_t)m * C_ + j;
      dst[0] = c[0] + bj;
      dst[C_] = c[1] + bj;
      dst[2 * C_] = c[2] + bj;
      dst[3 * C_] = c[3] + bj;
    }
  }
}

// ---------- attention: round-8 kernel; output stored as 2 bf16 planes ----------
__global__ __launch_bounds__(256) void attn_kernel(
    const float* __restrict__ qw, const float* __restrict__ kt,
    const float* __restrict__ vw, const float* __restrict__ fac,
    ushort_t* __restrict__ aoh, ushort_t* __restrict__ aom) {
  const int lane = threadIdx.x & 63;
  const int wid = threadIdx.x >> 6;
  const int qblk = blockIdx.x * 16;
  const int bh = qblk >> 10;
  const int b = bh >> 4, h = bh & 15;
  const int q0 = (qblk & (N_ - 1)) + wid * 4;

  __shared__ __align__(16) float q_ldsT[4][HD_][4];
  __shared__ unsigned su[4][64];
  __shared__ float sv[4][64];
  __shared__ int ck[4][64];
  __shared__ float cv[4][64];

  {
    const int qq = lane >> 4, dp = (lane & 15) << 2;
    const float4 v =
        *(const float4*)(qw + ((size_t)bh * N_ + q0 + qq) * HD_ + dp);
    q_ldsT[wid][dp + 0][qq] = v.x;
    q_ldsT[wid][dp + 1][qq] = v.y;
    q_ldsT[wid][dp + 2][qq] = v.z;
    q_ldsT[wid][dp + 3][qq] = v.w;
  }

  const float* ktb = kt + ((size_t)bh * HD_ * N_);
  const unsigned long long ltmask = (1ull << lane) - 1ull;
  unsigned u[4][16];

  for (int pass = 0; pass < 4; ++pass) {
    float acc[4][4];
#pragma unroll
    for (int a = 0; a < 4; ++a)
#pragma unroll
      for (int c = 0; c < 4; ++c) acc[a][c] = 0.f;
    const float* kp = ktb + (pass << 8) + (lane << 2);
#pragma unroll 4
    for (int d = 0; d < HD_; ++d) {
      const float4 kv = *(const float4*)(kp + (size_t)d * N_);
      const float4 qv = *(const float4*)(&q_ldsT[wid][d][0]);
      acc[0][0] = fmaf(kv.x, qv.x, acc[0][0]);
      acc[0][1] = fmaf(kv.x, qv.y, acc[0][1]);
      acc[0][2] = fmaf(kv.x, qv.z, acc[0][2]);
      acc[0][3] = fmaf(kv.x, qv.w, acc[0][3]);
      acc[1][0] = fmaf(kv.y, qv.x, acc[1][0]);
      acc[1][1] = fmaf(kv.y, qv.y, acc[1][1]);
      acc[1][2] = fmaf(kv.y, qv.z, acc[1][2]);
      acc[1][3] = fmaf(kv.y, qv.w, acc[1][3]);
      acc[2][0] = fmaf(kv.z, qv.x, acc[2][0]);
      acc[2][1] = fmaf(kv.z, qv.y, acc[2][1]);
      acc[2][2] = fmaf(kv.z, qv.z, acc[2][2]);
      acc[2][3] = fmaf(kv.z, qv.w, acc[2][3]);
      acc[3][0] = fmaf(kv.w, qv.x, acc[3][0]);
      acc[3][1] = fmaf(kv.w, qv.y, acc[3][1]);
      acc[3][2] = fmaf(kv.w, qv.z, acc[3][2]);
      acc[3][3] = fmaf(kv.w, qv.w, acc[3][3]);
    }
#pragma unroll
    for (int jl = 0; jl < 4; ++jl)
#pragma unroll
      for (int q = 0; q < 4; ++q)
        u[q][(pass << 2) + jl] = orderu((acc[jl][q] * 0.125f) / 0.8f);
  }

  unsigned mu[4], l0[4];
#pragma unroll
  for (int q = 0; q < 4; ++q) {
    unsigned mq = u[q][0];
#pragma unroll
    for (int j = 1; j < 16; ++j) mq = max(mq, u[q][j]);
    mu[q] = mq;
    l0[q] = mq;
  }
#pragma unroll
  for (int off = 32; off; off >>= 1) {
#pragma unroll
    for (int q = 0; q < 4; ++q) {
      mu[q] = max(mu[q], (unsigned)__shfl_xor((int)mu[q], off, 64));
      l0[q] = min(l0[q], (unsigned)__shfl_xor((int)l0[q], off, 64));
    }
  }

  unsigned lo[4], hi[4];
#pragma unroll
  for (int q = 0; q < 4; ++q) {
    lo[q] = l0[q];
    hi[q] = mu[q];
  }
  while ((lo[0] < hi[0]) | (lo[1] < hi[1]) | (lo[2] < hi[2]) |
         (lo[3] < hi[3])) {
#pragma unroll
    for (int q = 0; q < 4; ++q) {
      if (lo[q] < hi[q]) {
        const unsigned mid = lo[q] + ((hi[q] - lo[q]) >> 1) + 1u;
        int c = 0;
#pragma unroll
        for (int j = 0; j < 16; ++j)
          c += (int)__popcll(__ballot(u[q][j] >= mid));
        if (c >= 64) lo[q] = mid;
        else hi[q] = mid - 1u;
      }
    }
  }

  const float* vb = vw + ((size_t)bh << 16);
#pragma unroll
  for (int qq = 0; qq < 4; ++qq) {
    const unsigned kthu = lo[qq];
    const float m = iorderu(mu[qq]);

    float e[16];
    float zl = 0.f;
#pragma unroll
    for (int j = 0; j < 16; ++j) {
      const float ej = (u[qq][j] >= kthu) ? __expf(iorderu(u[qq][j]) - m) : 0.f;
      e[j] = ej;
      zl += ej;
    }
    const float Z = wsumf(zl);
    const float limit = 0.9f * Z;

    int base = 0;
#pragma unroll
    for (int j = 0; j < 16; ++j) {
      const bool f = (u[qq][j] >= kthu);
      const unsigned long long mb = __ballot(f);
      if (f) {
        const int pos = base + (int)__popcll(mb & ltmask);
        if (pos < 64) {
          su[wid][pos] = u[qq][j];
          sv[wid][pos] = e[j];
        }
      }
      base += (int)__popcll(mb);
    }

    unsigned sk = ~su[wid][lane];
    float se = sv[wid][lane];
#pragma unroll
    for (int k = 2; k <= 64; k <<= 1) {
#pragma unroll
      for (int j = k >> 1; j; j >>= 1) {
        const unsigned pk = (unsigned)__shfl_xor((int)sk, j, 64);
        const float pe = __shfl_xor(se, j, 64);
        const bool takeMin = (((lane & j) == 0) == ((lane & k) == 0));
        const bool sw = takeMin ? (pk < sk) : (pk > sk);
        if (sw) {
          sk = pk;
          se = pe;
        }
      }
    }

    float pre = se;
#pragma unroll
    for (int off = 1; off <= 32; off <<= 1) {
      const float t = __shfl_up(pre, off, 64);
      if (lane >= off) pre += t;
    }
    const float excl = pre - se;
    const bool keep = (excl <= limit);
    const unsigned long long km = __ballot(keep);
    const int L = 63 - __builtin_clzll(km);
    const unsigned thr = ~(unsigned)__shfl((int)sk, L, 64);

    float z2l = 0.f;
#pragma unroll
    for (int j = 0; j < 16; ++j) z2l += (u[qq][j] >= thr) ? e[j] : 0.f;
    const float Z2 = wsumf(z2l);
    const float wsc = fac[(b << 10) + q0 + qq] / Z2;

    int M = 0;
#pragma unroll
    for (int j = 0; j < 16; ++j) {
      const bool f = (u[qq][j] >= thr);
      const unsigned long long mb = __ballot(f);
      if (f) {
        const int pos = M + (int)__popcll(mb & ltmask);
        if (pos < 64) {
          ck[wid][pos] = ((j >> 2) << 8) + (lane << 2) + (j & 3);
          cv[wid][pos] = e[j] * wsc;
        }
      }
      M += (int)__popcll(mb);
    }
    if (M > 64) M = 64;

    float a0 = 0.f, a1 = 0.f, a2 = 0.f, a3 = 0.f;
    int i = 0;
    for (; i + 4 <= M; i += 4) {
      const int k0 = ck[wid][i], k1 = ck[wid][i + 1];
      const int k2 = ck[wid][i + 2], k3 = ck[wid][i + 3];
      const float c0 = cv[wid][i], c1 = cv[wid][i + 1];
      const float c2 = cv[wid][i + 2], c3 = cv[wid][i + 3];
      a0 = fmaf(c0, vb[((size_t)k0 << 6) + lane], a0);
      a1 = fmaf(c1, vb[((size_t)k1 << 6) + lane], a1);
      a2 = fmaf(c2, vb[((size_t)k2 << 6) + lane], a2);
      a3 = fmaf(c3, vb[((size_t)k3 << 6) + lane], a3);
    }
    for (; i < M; ++i)
      a0 = fmaf(cv[wid][i], vb[((size_t)ck[wid][i] << 6) + lane], a0);
    const float o = (a0 + a1) + (a2 + a3);

    // store as 2-term bf16 planes for the MFMA out-projection
    const unsigned pk2 = splitf2(o);
    const size_t idx = (((size_t)b << 10) + q0 + qq) * C_ + (h << 6) + lane;
    aoh[idx] = (ushort_t)(pk2 & 0xffffu);
    aom[idx] = (ushort_t)(pk2 >> 16);
  }
}

extern "C" void kernel_launch(void* const* d_in, const int* in_sizes, int n_in,
                              void* d_out, int out_size, void* d_ws,
                              size_t ws_size, hipStream_t stream) {
  const float* x = (const float*)d_in[0];
  const float* wqkv = (const float*)d_in[1];
  const float* wout = (const float*)d_in[2];
  const float* bout = (const float*)d_in[3];
  const float* alpha = (const float*)d_in[4];
  const float* beta = (const float*)d_in[5];
  float* out = (float*)d_out;

  float* ws = (float*)d_ws;
  const size_t M1 = 1u << 20;  // 1M floats
  float* qw = ws;               // 2M fl
  float* kt = ws + 2 * M1;      // 2M fl  [bh][d][n]
  float* vw = ws + 4 * M1;      // 2M fl
  float* fc = ws + 6 * M1;      // 2K fl (padded to 4K)
  ushort_t* xh = (ushort_t*)(ws + 6 * M1 + 4096);  // 1M fl each plane
  ushort_t* xm = (ushort_t*)(ws + 7 * M1 + 4096);
  ushort_t* xl = (ushort_t*)(ws + 8 * M1 + 4096);
  ushort_t* wqh = (ushort_t*)(ws + 9 * M1 + 4096);   // 1.5M fl each
  ushort_t* wqm = (ushort_t*)(ws + 10 * M1 + 4096 + M1 / 2);
  ushort_t* wql = (ushort_t*)(ws + 12 * M1 + 4096);
  // aliases (stream order makes these safe):
  ushort_t* woh = wql;                    // w_out planes overwrite wql
  ushort_t* wom = wql + M1;               // (wql dead after gemm_qk)
  ushort_t* wol = wql + 2 * M1;           // scratch third plane (unused)
  ushort_t* aoh = xh;                     // attn output planes overwrite
  ushort_t* aom = xm;                     // x planes (dead after gemm_v)

  split_x_kernel<<<2048, 256, 0, stream>>>(x, xh, xm, xl);
  split_wT_kernel<<<dim3(48, 16), 256, 0, stream>>>(wqkv, 3 * C_, wqh, wqm,
                                                    wql);
  factor_kernel<<<B_ * N_, 64, 0, stream>>>(x, alpha, beta, fc);
  gemm_qk_kernel<<<dim3(16, 16), 256, 0, stream>>>(xh, xm, xl, wqh, wqm, wql,
                                                   qw, kt);
  gemm_v_kernel<<<dim3(8, 16), 256, 0, stream>>>(xh, xm, wqh, wqm, vw);
  split_wT_kernel<<<dim3(16, 16), 256, 0, stream>>>(wout, C_, woh, wom, wol);
  attn_kernel<<<(B_ * H_ * N_) / 16, 256, 0, stream>>>(qw, kt, vw, fc, aoh,
                                                       aom);
  gemm_out_kernel<<<dim3(8, 16), 256, 0, stream>>>(aoh, aom, woh, wom, bout,
                                                   out);
}

// Round 12
// 417.536 us; speedup vs baseline: 1.3823x; 1.3823x over previous
//
#include <hip/hip_runtime.h>

#define B_ 2
#define N_ 1024
#define C_ 1024
#define H_ 16
#define HD_ 64
#define KPAD 36   // u32 per LDS row (144B stride): 16B-aligned b128 reads
#define KPADL 40  // u16 per LDS row (80B stride): 16B-aligned b128 reads

typedef short short8 __attribute__((ext_vector_type(8)));
typedef float f32x4 __attribute__((ext_vector_type(4)));

union U16 {
  uint4 q;
  unsigned u[4];
  short8 s;
};

// ---------- wave-wide (64-lane) helpers ----------
__device__ __forceinline__ float wsumf(float x) {
#pragma unroll
  for (int off = 32; off; off >>= 1) x += __shfl_xor(x, off, 64);
  return x;
}
__device__ __forceinline__ unsigned orderu(float f) {
  unsigned b = __float_as_uint(f);
  return (b & 0x80000000u) ? ~b : (b | 0x80000000u);
}
__device__ __forceinline__ float iorderu(unsigned x) {
  unsigned b = (x & 0x80000000u) ? (x & 0x7FFFFFFFu) : ~x;
  return __uint_as_float(b);
}

// 2-term split f32 -> packed u32: hi bf16 low16, lo bf16 high16 (RTNE)
__device__ __forceinline__ unsigned splitf2(float f) {
  unsigned u = __float_as_uint(f);
  unsigned t = (u + 0x7fffu + ((u >> 16) & 1u)) & 0xffff0000u;
  float r = f - __uint_as_float(t);  // exact
  unsigned v = __float_as_uint(r);
  unsigned tv = v + 0x7fffu + ((v >> 16) & 1u);
  return (t >> 16) | (tv & 0xffff0000u);
}
// 3-term split: hm = hi|mid packed u32, lo = third bf16 term
__device__ __forceinline__ void splitf3(float f, unsigned& hm,
                                        unsigned short& lo) {
  unsigned u = __float_as_uint(f);
  unsigned t = (u + 0x7fffu + ((u >> 16) & 1u)) & 0xffff0000u;
  float r1 = f - __uint_as_float(t);  // exact
  unsigned v = __float_as_uint(r1);
  unsigned tv = (v + 0x7fffu + ((v >> 16) & 1u)) & 0xffff0000u;
  float r2 = r1 - __uint_as_float(tv);  // exact
  unsigned w = __float_as_uint(r2);
  unsigned tw = w + 0x7fffu + ((w >> 16) & 1u);
  hm = (t >> 16) | tv;
  lo = (unsigned short)(tw >> 16);
}

__device__ __forceinline__ void unpack_hm(const unsigned* p, short8& h,
                                          short8& l) {
  const uint4 X = *(const uint4*)p;
  const uint4 Y = *(const uint4*)(p + 4);
  U16 Hh, Ll;
  Hh.u[0] = (X.x & 0xffffu) | (X.y << 16);
  Hh.u[1] = (X.z & 0xffffu) | (X.w << 16);
  Hh.u[2] = (Y.x & 0xffffu) | (Y.y << 16);
  Hh.u[3] = (Y.z & 0xffffu) | (Y.w << 16);
  Ll.u[0] = (X.x >> 16) | (X.y & 0xffff0000u);
  Ll.u[1] = (X.z >> 16) | (X.w & 0xffff0000u);
  Ll.u[2] = (Y.x >> 16) | (Y.y & 0xffff0000u);
  Ll.u[3] = (Y.z >> 16) | (Y.w & 0xffff0000u);
  h = Hh.s;
  l = Ll.s;
}

// ---------- NKAT per-token factor ----------
__global__ __launch_bounds__(64) void factor_kernel(
    const float* __restrict__ x, const float* __restrict__ alpha_p,
    const float* __restrict__ beta_p, float* __restrict__ fac) {
  const int row = blockIdx.x;
  const int lane = threadIdx.x;
  const float4* xr = (const float4*)(x + (size_t)row * C_);
  float s = 0.f, ss = 0.f;
#pragma unroll
  for (int j = 0; j < 4; ++j) {
    float4 v = xr[lane + 64 * j];
    s += v.x + v.y + v.z + v.w;
    ss += v.x * v.x + v.y * v.y + v.z * v.z + v.w * v.w;
  }
  s = wsumf(s);
  ss = wsumf(ss);
  const float mean = s * (1.f / 1024.f);
  const float var = ss * (1.f / 1024.f) - mean * mean;
  const float theta =
      alpha_p[0] * tanhf(mean) + beta_p[0] * (1.f / (1.f + __expf(-var)));
  if (lane == 0) fac[row] = 1.f + 0.45125f * theta;  // lc = 0.5*0.95^2
}

// ---------- 3-term split MFMA core, 128x64 tile, BK=32, 4 waves (2x2) ----------
// 6 products {h*l, l*h, m*m, h*m, m*h, h*h}, smallest-first (q/k precision).
__device__ __forceinline__ void mfma_core6(
    const float* __restrict__ A, const float* __restrict__ Bm, int lda,
    int ldb, int m0, int n0, unsigned* a_hm, unsigned* b_hm,
    unsigned short* a_lo, unsigned short* b_lo, f32x4 acc[4][2]) {
  const int tid = threadIdx.x;
  const int lane = tid & 63;
  const int wro = ((tid >> 7) & 1) * 64;  // wave row offset (0/64)
  const int wco = ((tid >> 6) & 1) * 32;  // wave col offset (0/32)
  const int a_k4 = (tid & 7) * 4, a_m = tid >> 3;  // A rows a_m+32j
  const int b_k = tid >> 4;                        // B k-rows b_k, b_k+16
  const int b_j4 = (tid & 15) * 4;                 // B col chunk
  const int fr = lane & 15, fk = (lane >> 4) * 8;

  float4 aR[4], bR[2];
#pragma unroll
  for (int j = 0; j < 4; ++j)
    aR[j] = *(const float4*)(A + (size_t)(m0 + a_m + 32 * j) * lda + a_k4);
  bR[0] = *(const float4*)(Bm + (size_t)b_k * ldb + n0 + b_j4);
  bR[1] = *(const float4*)(Bm + (size_t)(b_k + 16) * ldb + n0 + b_j4);

  for (int kt = 0; kt < 32; ++kt) {
    __syncthreads();  // prior iteration's frag reads done
#pragma unroll
    for (int j = 0; j < 4; ++j) {
      uint4 w;
      ushort4 l;
      splitf3(aR[j].x, w.x, l.x);
      splitf3(aR[j].y, w.y, l.y);
      splitf3(aR[j].z, w.z, l.z);
      splitf3(aR[j].w, w.w, l.w);
      *(uint4*)(a_hm + (a_m + 32 * j) * KPAD + a_k4) = w;
      *(ushort4*)(a_lo + (a_m + 32 * j) * KPADL + a_k4) = l;
    }
    {
      unsigned hm;
      unsigned short lo;
      splitf3(bR[0].x, hm, lo);
      b_hm[(b_j4 + 0) * KPAD + b_k] = hm;
      b_lo[(b_j4 + 0) * KPADL + b_k] = lo;
      splitf3(bR[0].y, hm, lo);
      b_hm[(b_j4 + 1) * KPAD + b_k] = hm;
      b_lo[(b_j4 + 1) * KPADL + b_k] = lo;
      splitf3(bR[0].z, hm, lo);
      b_hm[(b_j4 + 2) * KPAD + b_k] = hm;
      b_lo[(b_j4 + 2) * KPADL + b_k] = lo;
      splitf3(bR[0].w, hm, lo);
      b_hm[(b_j4 + 3) * KPAD + b_k] = hm;
      b_lo[(b_j4 + 3) * KPADL + b_k] = lo;
      splitf3(bR[1].x, hm, lo);
      b_hm[(b_j4 + 0) * KPAD + b_k + 16] = hm;
      b_lo[(b_j4 + 0) * KPADL + b_k + 16] = lo;
      splitf3(bR[1].y, hm, lo);
      b_hm[(b_j4 + 1) * KPAD + b_k + 16] = hm;
      b_lo[(b_j4 + 1) * KPADL + b_k + 16] = lo;
      splitf3(bR[1].z, hm, lo);
      b_hm[(b_j4 + 2) * KPAD + b_k + 16] = hm;
      b_lo[(b_j4 + 2) * KPADL + b_k + 16] = lo;
      splitf3(bR[1].w, hm, lo);
      b_hm[(b_j4 + 3) * KPAD + b_k + 16] = hm;
      b_lo[(b_j4 + 3) * KPADL + b_k + 16] = lo;
    }
    __syncthreads();
    if (kt + 1 < 32) {  // prefetch next k-tile; hides under MFMA
      const int kb = (kt + 1) * 32;
#pragma unroll
      for (int j = 0; j < 4; ++j)
        aR[j] =
            *(const float4*)(A + (size_t)(m0 + a_m + 32 * j) * lda + kb + a_k4);
      bR[0] = *(const float4*)(Bm + (size_t)(kb + b_k) * ldb + n0 + b_j4);
      bR[1] = *(const float4*)(Bm + (size_t)(kb + b_k + 16) * ldb + n0 + b_j4);
    }
    short8 ah[4], am[4], al[4];
#pragma unroll
    for (int rt = 0; rt < 4; ++rt) {
      const int row = wro + rt * 16 + fr;
      unpack_hm(a_hm + row * KPAD + fk, ah[rt], am[rt]);
      U16 L;
      L.q = *(const uint4*)(a_lo + row * KPADL + fk);
      al[rt] = L.s;
    }
#pragma unroll
    for (int ct = 0; ct < 2; ++ct) {
      const int row = wco + ct * 16 + fr;
      short8 bh, bm, bl;
      unpack_hm(b_hm + row * KPAD + fk, bh, bm);
      U16 L;
      L.q = *(const uint4*)(b_lo + row * KPADL + fk);
      bl = L.s;
#pragma unroll
      for (int rt = 0; rt < 4; ++rt) {
        f32x4 c = acc[rt][ct];
        c = __builtin_amdgcn_mfma_f32_16x16x32_bf16(ah[rt], bl, c, 0, 0, 0);
        c = __builtin_amdgcn_mfma_f32_16x16x32_bf16(al[rt], bh, c, 0, 0, 0);
        c = __builtin_amdgcn_mfma_f32_16x16x32_bf16(am[rt], bm, c, 0, 0, 0);
        c = __builtin_amdgcn_mfma_f32_16x16x32_bf16(ah[rt], bm, c, 0, 0, 0);
        c = __builtin_amdgcn_mfma_f32_16x16x32_bf16(am[rt], bh, c, 0, 0, 0);
        c = __builtin_amdgcn_mfma_f32_16x16x32_bf16(ah[rt], bh, c, 0, 0, 0);
        acc[rt][ct] = c;
      }
    }
  }
}

// ---------- 2-term split MFMA core, 128x64 tile (v / out-proj) ----------
// 3 products {h*l, l*h, h*h}, smallest-first.
__device__ __forceinline__ void mfma_core3(const float* __restrict__ A,
                                           const float* __restrict__ Bm,
                                           int lda, int ldb, int m0, int n0,
                                           unsigned* a_hm, unsigned* b_hm,
                                           f32x4 acc[4][2]) {
  const int tid = threadIdx.x;
  const int lane = tid & 63;
  const int wro = ((tid >> 7) & 1) * 64;
  const int wco = ((tid >> 6) & 1) * 32;
  const int a_k4 = (tid & 7) * 4, a_m = tid >> 3;
  const int b_k = tid >> 4;
  const int b_j4 = (tid & 15) * 4;
  const int fr = lane & 15, fk = (lane >> 4) * 8;

  float4 aR[4], bR[2];
#pragma unroll
  for (int j = 0; j < 4; ++j)
    aR[j] = *(const float4*)(A + (size_t)(m0 + a_m + 32 * j) * lda + a_k4);
  bR[0] = *(const float4*)(Bm + (size_t)b_k * ldb + n0 + b_j4);
  bR[1] = *(const float4*)(Bm + (size_t)(b_k + 16) * ldb + n0 + b_j4);

  for (int kt = 0; kt < 32; ++kt) {
    __syncthreads();
#pragma unroll
    for (int j = 0; j < 4; ++j) {
      uint4 w;
      w.x = splitf2(aR[j].x);
      w.y = splitf2(aR[j].y);
      w.z = splitf2(aR[j].z);
      w.w = splitf2(aR[j].w);
      *(uint4*)(a_hm + (a_m + 32 * j) * KPAD + a_k4) = w;
    }
    {
      b_hm[(b_j4 + 0) * KPAD + b_k] = splitf2(bR[0].x);
      b_hm[(b_j4 + 1) * KPAD + b_k] = splitf2(bR[0].y);
      b_hm[(b_j4 + 2) * KPAD + b_k] = splitf2(bR[0].z);
      b_hm[(b_j4 + 3) * KPAD + b_k] = splitf2(bR[0].w);
      b_hm[(b_j4 + 0) * KPAD + b_k + 16] = splitf2(bR[1].x);
      b_hm[(b_j4 + 1) * KPAD + b_k + 16] = splitf2(bR[1].y);
      b_hm[(b_j4 + 2) * KPAD + b_k + 16] = splitf2(bR[1].z);
      b_hm[(b_j4 + 3) * KPAD + b_k + 16] = splitf2(bR[1].w);
    }
    __syncthreads();
    if (kt + 1 < 32) {
      const int kb = (kt + 1) * 32;
#pragma unroll
      for (int j = 0; j < 4; ++j)
        aR[j] =
            *(const float4*)(A + (size_t)(m0 + a_m + 32 * j) * lda + kb + a_k4);
      bR[0] = *(const float4*)(Bm + (size_t)(kb + b_k) * ldb + n0 + b_j4);
      bR[1] = *(const float4*)(Bm + (size_t)(kb + b_k + 16) * ldb + n0 + b_j4);
    }
    short8 ah[4], al[4];
#pragma unroll
    for (int rt = 0; rt < 4; ++rt)
      unpack_hm(a_hm + (wro + rt * 16 + fr) * KPAD + fk, ah[rt], al[rt]);
#pragma unroll
    for (int ct = 0; ct < 2; ++ct) {
      short8 bh, bl;
      unpack_hm(b_hm + (wco + ct * 16 + fr) * KPAD + fk, bh, bl);
#pragma unroll
      for (int rt = 0; rt < 4; ++rt) {
        f32x4 c = acc[rt][ct];
        c = __builtin_amdgcn_mfma_f32_16x16x32_bf16(ah[rt], bl, c, 0, 0, 0);
        c = __builtin_amdgcn_mfma_f32_16x16x32_bf16(al[rt], bh, c, 0, 0, 0);
        c = __builtin_amdgcn_mfma_f32_16x16x32_bf16(ah[rt], bh, c, 0, 0, 0);
        acc[rt][ct] = c;
      }
    }
  }
}

// ---------- qk: columns 0..2047 of x@w_qkv -> q (B,H,N,HD), kt [bh][d][n] ----------
__global__ __launch_bounds__(256) void gemm_qk_kernel(
    const float* __restrict__ x, const float* __restrict__ w,
    float* __restrict__ q, float* __restrict__ ktb) {
  __shared__ unsigned a_hm[128 * KPAD];
  __shared__ unsigned b_hm[64 * KPAD];
  __shared__ unsigned short a_lo[128 * KPADL];
  __shared__ unsigned short b_lo[64 * KPADL];
  f32x4 acc[4][2];
#pragma unroll
  for (int i = 0; i < 4; ++i)
#pragma unroll
    for (int j = 0; j < 2; ++j) acc[i][j] = (f32x4){0.f, 0.f, 0.f, 0.f};
  const int m0 = blockIdx.y * 128, n0 = blockIdx.x * 64;
  mfma_core6(x, w, C_, 3 * C_, m0, n0, a_hm, b_hm, a_lo, b_lo, acc);

  const int lane = threadIdx.x & 63;
  const int wro = ((threadIdx.x >> 7) & 1) * 64;
  const int wco = ((threadIdx.x >> 6) & 1) * 32;
  const int rbase = (lane >> 4) * 4, cc = lane & 15;
#pragma unroll
  for (int rt = 0; rt < 4; ++rt) {
    const int m = m0 + wro + rt * 16 + rbase;
    const int bb2 = m >> 10, nn = m & 1023;
#pragma unroll
    for (int ct = 0; ct < 2; ++ct) {
      const int j = n0 + wco + ct * 16 + cc;
      const int sel = j >> 10, hh = (j >> 6) & 15, d0 = j & 63;
      const f32x4 c = acc[rt][ct];
      if (sel == 1) {  // K transposed: contiguous along token index nn
        *(float4*)(ktb + (((size_t)(bb2 * 16 + hh) * HD_ + d0) << 10) + nn) =
            make_float4(c[0], c[1], c[2], c[3]);
      } else {
        float* dst = q + (((size_t)(bb2 * 16 + hh) << 10) + nn) * HD_ + d0;
        dst[0] = c[0];
        dst[HD_] = c[1];
        dst[2 * HD_] = c[2];
        dst[3 * HD_] = c[3];
      }
    }
  }
}

// ---------- v: w_qkv cols 2048..3071 -> v (B,H,N,HD) ----------
__global__ __launch_bounds__(256) void gemm_v_kernel(
    const float* __restrict__ x, const float* __restrict__ w,
    float* __restrict__ v) {
  __shared__ unsigned a_hm[128 * KPAD];
  __shared__ unsigned b_hm[64 * KPAD];
  f32x4 acc[4][2];
#pragma unroll
  for (int i = 0; i < 4; ++i)
#pragma unroll
    for (int j = 0; j < 2; ++j) acc[i][j] = (f32x4){0.f, 0.f, 0.f, 0.f};
  const int m0 = blockIdx.y * 128, n0 = 2048 + blockIdx.x * 64;
  mfma_core3(x, w, C_, 3 * C_, m0, n0, a_hm, b_hm, acc);

  const int lane = threadIdx.x & 63;
  const int wro = ((threadIdx.x >> 7) & 1) * 64;
  const int wco = ((threadIdx.x >> 6) & 1) * 32;
  const int rbase = (lane >> 4) * 4, cc = lane & 15;
#pragma unroll
  for (int rt = 0; rt < 4; ++rt) {
    const int m = m0 + wro + rt * 16 + rbase;
    const int bb = m >> 10, nn = m & 1023;
#pragma unroll
    for (int ct = 0; ct < 2; ++ct) {
      const int jv = (n0 - 2048) + wco + ct * 16 + cc;
      const int hh = (jv >> 6) & 15, d0 = jv & 63;
      const f32x4 c = acc[rt][ct];
      float* dst = v + (((size_t)(bb * 16 + hh) << 10) + nn) * HD_ + d0;
      dst[0] = c[0];
      dst[HD_] = c[1];
      dst[2 * HD_] = c[2];
      dst[3 * HD_] = c[3];
    }
  }
}

// ---------- out = attn_out @ w_out + b_out ----------
__global__ __launch_bounds__(256) void gemm_out_kernel(
    const float* __restrict__ a, const float* __restrict__ w,
    const float* __restrict__ bias, float* __restrict__ out) {
  __shared__ unsigned a_hm[128 * KPAD];
  __shared__ unsigned b_hm[64 * KPAD];
  f32x4 acc[4][2];
#pragma unroll
  for (int i = 0; i < 4; ++i)
#pragma unroll
    for (int j = 0; j < 2; ++j) acc[i][j] = (f32x4){0.f, 0.f, 0.f, 0.f};
  const int m0 = blockIdx.y * 128, n0 = blockIdx.x * 64;
  mfma_core3(a, w, C_, C_, m0, n0, a_hm, b_hm, acc);

  const int lane = threadIdx.x & 63;
  const int wro = ((threadIdx.x >> 7) & 1) * 64;
  const int wco = ((threadIdx.x >> 6) & 1) * 32;
  const int rbase = (lane >> 4) * 4, cc = lane & 15;
#pragma unroll
  for (int rt = 0; rt < 4; ++rt) {
    const int m = m0 + wro + rt * 16 + rbase;
#pragma unroll
    for (int ct = 0; ct < 2; ++ct) {
      const int j = n0 + wco + ct * 16 + cc;
      const float bj = bias[j];
      const f32x4 c = acc[rt][ct];
      float* dst = out + (size_t)m * C_ + j;
      dst[0] = c[0] + bj;
      dst[C_] = c[1] + bj;
      dst[2 * C_] = c[2] + bj;
      dst[3 * C_] = c[3] + bj;
    }
  }
}

// ---------- attention: round-8/10 kernel, unchanged (verified) ----------
__global__ __launch_bounds__(256) void attn_kernel(
    const float* __restrict__ qw, const float* __restrict__ kt,
    const float* __restrict__ vw, const float* __restrict__ fac,
    float* __restrict__ ao) {
  const int lane = threadIdx.x & 63;
  const int wid = threadIdx.x >> 6;
  const int qblk = blockIdx.x * 16;
  const int bh = qblk >> 10;
  const int b = bh >> 4, h = bh & 15;
  const int q0 = (qblk & (N_ - 1)) + wid * 4;

  __shared__ __align__(16) float q_ldsT[4][HD_][4];
  __shared__ unsigned su[4][64];
  __shared__ float sv[4][64];
  __shared__ int ck[4][64];
  __shared__ float cv[4][64];

  {
    const int qq = lane >> 4, dp = (lane & 15) << 2;
    const float4 v =
        *(const float4*)(qw + ((size_t)bh * N_ + q0 + qq) * HD_ + dp);
    q_ldsT[wid][dp + 0][qq] = v.x;
    q_ldsT[wid][dp + 1][qq] = v.y;
    q_ldsT[wid][dp + 2][qq] = v.z;
    q_ldsT[wid][dp + 3][qq] = v.w;
  }

  const float* ktb = kt + ((size_t)bh * HD_ * N_);
  const unsigned long long ltmask = (1ull << lane) - 1ull;
  unsigned u[4][16];

  for (int pass = 0; pass < 4; ++pass) {
    float acc[4][4];
#pragma unroll
    for (int a = 0; a < 4; ++a)
#pragma unroll
      for (int c = 0; c < 4; ++c) acc[a][c] = 0.f;
    const float* kp = ktb + (pass << 8) + (lane << 2);
#pragma unroll 4
    for (int d = 0; d < HD_; ++d) {
      const float4 kv = *(const float4*)(kp + (size_t)d * N_);
      const float4 qv = *(const float4*)(&q_ldsT[wid][d][0]);
      acc[0][0] = fmaf(kv.x, qv.x, acc[0][0]);
      acc[0][1] = fmaf(kv.x, qv.y, acc[0][1]);
      acc[0][2] = fmaf(kv.x, qv.z, acc[0][2]);
      acc[0][3] = fmaf(kv.x, qv.w, acc[0][3]);
      acc[1][0] = fmaf(kv.y, qv.x, acc[1][0]);
      acc[1][1] = fmaf(kv.y, qv.y, acc[1][1]);
      acc[1][2] = fmaf(kv.y, qv.z, acc[1][2]);
      acc[1][3] = fmaf(kv.y, qv.w, acc[1][3]);
      acc[2][0] = fmaf(kv.z, qv.x, acc[2][0]);
      acc[2][1] = fmaf(kv.z, qv.y, acc[2][1]);
      acc[2][2] = fmaf(kv.z, qv.z, acc[2][2]);
      acc[2][3] = fmaf(kv.z, qv.w, acc[2][3]);
      acc[3][0] = fmaf(kv.w, qv.x, acc[3][0]);
      acc[3][1] = fmaf(kv.w, qv.y, acc[3][1]);
      acc[3][2] = fmaf(kv.w, qv.z, acc[3][2]);
      acc[3][3] = fmaf(kv.w, qv.w, acc[3][3]);
    }
#pragma unroll
    for (int jl = 0; jl < 4; ++jl)
#pragma unroll
      for (int q = 0; q < 4; ++q)
        u[q][(pass << 2) + jl] = orderu((acc[jl][q] * 0.125f) / 0.8f);
  }

  unsigned mu[4], l0[4];
#pragma unroll
  for (int q = 0; q < 4; ++q) {
    unsigned mq = u[q][0];
#pragma unroll
    for (int j = 1; j < 16; ++j) mq = max(mq, u[q][j]);
    mu[q] = mq;
    l0[q] = mq;
  }
#pragma unroll
  for (int off = 32; off; off >>= 1) {
#pragma unroll
    for (int q = 0; q < 4; ++q) {
      mu[q] = max(mu[q], (unsigned)__shfl_xor((int)mu[q], off, 64));
      l0[q] = min(l0[q], (unsigned)__shfl_xor((int)l0[q], off, 64));
    }
  }

  unsigned lo[4], hi[4];
#pragma unroll
  for (int q = 0; q < 4; ++q) {
    lo[q] = l0[q];
    hi[q] = mu[q];
  }
  while ((lo[0] < hi[0]) | (lo[1] < hi[1]) | (lo[2] < hi[2]) |
         (lo[3] < hi[3])) {
#pragma unroll
    for (int q = 0; q < 4; ++q) {
      if (lo[q] < hi[q]) {
        const unsigned mid = lo[q] + ((hi[q] - lo[q]) >> 1) + 1u;
        int c = 0;
#pragma unroll
        for (int j = 0; j < 16; ++j)
          c += (int)__popcll(__ballot(u[q][j] >= mid));
        if (c >= 64) lo[q] = mid;
        else hi[q] = mid - 1u;
      }
    }
  }

  const float* vb = vw + ((size_t)bh << 16);
#pragma unroll
  for (int qq = 0; qq < 4; ++qq) {
    const unsigned kthu = lo[qq];
    const float m = iorderu(mu[qq]);

    float e[16];
    float zl = 0.f;
#pragma unroll
    for (int j = 0; j < 16; ++j) {
      const float ej = (u[qq][j] >= kthu) ? __expf(iorderu(u[qq][j]) - m) : 0.f;
      e[j] = ej;
      zl += ej;
    }
    const float Z = wsumf(zl);
    const float limit = 0.9f * Z;

    int base = 0;
#pragma unroll
    for (int j = 0; j < 16; ++j) {
      const bool f = (u[qq][j] >= kthu);
      const unsigned long long mb = __ballot(f);
      if (f) {
        const int pos = base + (int)__popcll(mb & ltmask);
        if (pos < 64) {
          su[wid][pos] = u[qq][j];
          sv[wid][pos] = e[j];
        }
      }
      base += (int)__popcll(mb);
    }

    unsigned sk = ~su[wid][lane];
    float se = sv[wid][lane];
#pragma unroll
    for (int k = 2; k <= 64; k <<= 1) {
#pragma unroll
      for (int j = k >> 1; j; j >>= 1) {
        const unsigned pk = (unsigned)__shfl_xor((int)sk, j, 64);
        const float pe = __shfl_xor(se, j, 64);
        const bool takeMin = (((lane & j) == 0) == ((lane & k) == 0));
        const bool sw = takeMin ? (pk < sk) : (pk > sk);
        if (sw) {
          sk = pk;
          se = pe;
        }
      }
    }

    float pre = se;
#pragma unroll
    for (int off = 1; off <= 32; off <<= 1) {
      const float t = __shfl_up(pre, off, 64);
      if (lane >= off) pre += t;
    }
    const float excl = pre - se;
    const bool keep = (excl <= limit);
    const unsigned long long km = __ballot(keep);
    const int L = 63 - __builtin_clzll(km);
    const unsigned thr = ~(unsigned)__shfl((int)sk, L, 64);

    float z2l = 0.f;
#pragma unroll
    for (int j = 0; j < 16; ++j) z2l += (u[qq][j] >= thr) ? e[j] : 0.f;
    const float Z2 = wsumf(z2l);
    const float wsc = fac[(b << 10) + q0 + qq] / Z2;

    int M = 0;
#pragma unroll
    for (int j = 0; j < 16; ++j) {
      const bool f = (u[qq][j] >= thr);
      const unsigned long long mb = __ballot(f);
      if (f) {
        const int pos = M + (int)__popcll(mb & ltmask);
        if (pos < 64) {
          ck[wid][pos] = ((j >> 2) << 8) + (lane << 2) + (j & 3);
          cv[wid][pos] = e[j] * wsc;
        }
      }
      M += (int)__popcll(mb);
    }
    if (M > 64) M = 64;

    float a0 = 0.f, a1 = 0.f, a2 = 0.f, a3 = 0.f;
    int i = 0;
    for (; i + 4 <= M; i += 4) {
      const int k0 = ck[wid][i], k1 = ck[wid][i + 1];
      const int k2 = ck[wid][i + 2], k3 = ck[wid][i + 3];
      const float c0 = cv[wid][i], c1 = cv[wid][i + 1];
      const float c2 = cv[wid][i + 2], c3 = cv[wid][i + 3];
      a0 = fmaf(c0, vb[((size_t)k0 << 6) + lane], a0);
      a1 = fmaf(c1, vb[((size_t)k1 << 6) + lane], a1);
      a2 = fmaf(c2, vb[((size_t)k2 << 6) + lane], a2);
      a3 = fmaf(c3, vb[((size_t)k3 << 6) + lane], a3);
    }
    for (; i < M; ++i)
      a0 = fmaf(cv[wid][i], vb[((size_t)ck[wid][i] << 6) + lane], a0);
    const float o = (a0 + a1) + (a2 + a3);

    ao[(((size_t)b << 10) + q0 + qq) * C_ + (h << 6) + lane] = o;
  }
}

extern "C" void kernel_launch(void* const* d_in, const int* in_sizes, int n_in,
                              void* d_out, int out_size, void* d_ws,
                              size_t ws_size, hipStream_t stream) {
  const float* x = (const float*)d_in[0];
  const float* wqkv = (const float*)d_in[1];
  const float* wout = (const float*)d_in[2];
  const float* bout = (const float*)d_in[3];
  const float* alpha = (const float*)d_in[4];
  const float* beta = (const float*)d_in[5];
  float* out = (float*)d_out;

  float* ws = (float*)d_ws;
  const size_t SZ = (size_t)B_ * H_ * N_ * HD_;  // 2M floats
  float* qw = ws;
  float* kt = ws + SZ;  // K transposed per head: [bh][d][n]
  float* vw = ws + 2 * SZ;
  float* ao = ws + 3 * SZ;
  float* fc = ws + 4 * SZ;

  factor_kernel<<<B_ * N_, 64, 0, stream>>>(x, alpha, beta, fc);
  gemm_qk_kernel<<<dim3(32, 16), 256, 0, stream>>>(x, wqkv, qw, kt);
  gemm_v_kernel<<<dim3(16, 16), 256, 0, stream>>>(x, wqkv, vw);
  attn_kernel<<<(B_ * H_ * N_) / 16, 256, 0, stream>>>(qw, kt, vw, fc, ao);
  gemm_out_kernel<<<dim3(16, 16), 256, 0, stream>>>(ao, wout, bout, out);
}